// Round 1
// baseline (660.646 us; speedup 1.0000x reference)
//
#include <hip/hip_runtime.h>
#include <hip/hip_bf16.h>

#define SEQ 512
#define FEAT 64
#define HID 32
#define NCLS 10
#define BATCH 2048

// ---------------------------------------------------------------------------
// Phase 1: XW[b][h][t] (bf16) = x[b][t][:] . W_ih[h][:] + (b_ih[h] + b_hh[h])
// Block = 256 threads = 2 batches x 128 t-chunks (4 consecutive t per thread).
// Loads of x are contiguous per thread (1 KiB each, wave covers 64 KiB).
// Stores go through a 64 KiB LDS transpose so global writes are coalesced
// dwordx4 into the [b][h][t] layout phase 2 wants.
// ---------------------------------------------------------------------------
__global__ __launch_bounds__(256, 2) void xw_kernel(
    const float* __restrict__ x,     // [B, S, F]
    const float* __restrict__ W_ih,  // [H, F]
    const float* __restrict__ b_ih,  // [H]
    const float* __restrict__ b_hh,  // [H]
    unsigned short* __restrict__ xw) // [B, H, S] bf16 bits
{
    __shared__ float wl[HID * FEAT];            // 8 KiB
    __shared__ float bias[HID];
    __shared__ unsigned short xt[2 * HID * SEQ]; // 64 KiB: [b2][h][t]

    const int tid = threadIdx.x;

    // stage W_ih and fused bias
#pragma unroll
    for (int i = 0; i < 8; i++) wl[tid + 256 * i] = W_ih[tid + 256 * i];
    if (tid < HID) bias[tid] = b_ih[tid] + b_hh[tid];
    __syncthreads();

    const int b2 = tid >> 7;          // 0..1 (batch within block)
    const int t0 = (tid & 127) << 2;  // 0,4,...,508
    const int b  = blockIdx.x * 2 + b2;
    const float* xrow = x + ((size_t)b * SEQ + t0) * FEAT;

    float acc[4][HID];
#pragma unroll
    for (int r = 0; r < 4; r++)
#pragma unroll
        for (int h = 0; h < HID; h++) acc[r][h] = 0.f;

    const float4* wl4 = (const float4*)wl;

    float4 xv[4];
#pragma unroll
    for (int r = 0; r < 4; r++) xv[r] = *(const float4*)(xrow + r * FEAT);

#pragma unroll 1
    for (int f4 = 0; f4 < FEAT / 4; f4++) {
        float4 xc[4];
#pragma unroll
        for (int r = 0; r < 4; r++) xc[r] = xv[r];
        if (f4 < FEAT / 4 - 1) {
#pragma unroll
            for (int r = 0; r < 4; r++)
                xv[r] = *(const float4*)(xrow + r * FEAT + (f4 + 1) * 4);
        }
#pragma unroll
        for (int h = 0; h < HID; h++) {
            float4 wv = wl4[h * (FEAT / 4) + f4];
#pragma unroll
            for (int r = 0; r < 4; r++) {
                acc[r][h] = fmaf(xc[r].x, wv.x, acc[r][h]);
                acc[r][h] = fmaf(xc[r].y, wv.y, acc[r][h]);
                acc[r][h] = fmaf(xc[r].z, wv.z, acc[r][h]);
                acc[r][h] = fmaf(xc[r].w, wv.w, acc[r][h]);
            }
        }
    }

    // bias add + bf16 convert + transpose into LDS [b2][h][t]
#pragma unroll
    for (int h = 0; h < HID; h++) {
        float bsum = bias[h];
        ushort4 v;
        __hip_bfloat16 q0 = __float2bfloat16(acc[0][h] + bsum);
        __hip_bfloat16 q1 = __float2bfloat16(acc[1][h] + bsum);
        __hip_bfloat16 q2 = __float2bfloat16(acc[2][h] + bsum);
        __hip_bfloat16 q3 = __float2bfloat16(acc[3][h] + bsum);
        v.x = *(unsigned short*)&q0;
        v.y = *(unsigned short*)&q1;
        v.z = *(unsigned short*)&q2;
        v.w = *(unsigned short*)&q3;
        *(ushort4*)&xt[(b2 * HID + h) * SEQ + t0] = v;
    }
    __syncthreads();

    // coalesced copy-out of the 64 KiB block image (layout already matches)
    const uint4* src = (const uint4*)xt;
    uint4* dst = (uint4*)(xw + (size_t)blockIdx.x * 2 * HID * SEQ);
#pragma unroll
    for (int k = 0; k < 16; k++) dst[tid + 256 * k] = src[tid + 256 * k];
}

// ---------------------------------------------------------------------------
// Phase 2: recurrence + FC head.
// Lane = (batch, j). Each lane: W_hh row j in 32 VGPRs, full replicated h[32]
// in 32 VGPRs. Per step: 32 fp32 FMAs (4 accumulators), fast tanh, then
// re-replicate h via 1 ds_write_b32 + 8 broadcast ds_read_b128 (wave-local,
// in-order DS pipe -> no barrier needed; each wave owns its 2 LDS rows).
// ---------------------------------------------------------------------------
__device__ __forceinline__ float tanh_fast(float v) {
    float e = __expf(2.f * v);
    return 1.f - 2.f / (e + 1.f);
}

__global__ __launch_bounds__(256) void rnn_kernel(
    const unsigned short* __restrict__ xw, // [B, H, S] bf16 bits
    const float* __restrict__ W_hh,        // [H, H]
    const float* __restrict__ fc_W,        // [NCLS, H]
    const float* __restrict__ fc_b,        // [NCLS]
    float* __restrict__ out)               // [B, NCLS]
{
    __shared__ float hl[8 * HID]; // 8 batches per block

    const int tid = threadIdx.x;
    const int j   = tid & 31;
    const int bl  = tid >> 5; // 0..7
    const int b   = blockIdx.x * 8 + bl;

    float w[HID];
#pragma unroll
    for (int k = 0; k < HID; k++) w[k] = W_hh[j * HID + k];

    float h[HID];
#pragma unroll
    for (int k = 0; k < HID; k++) h[k] = 0.f;

    const unsigned short* xwp = xw + ((size_t)b * HID + j) * SEQ;
    float* hrow = &hl[bl * HID];

#pragma unroll 1
    for (int t8 = 0; t8 < SEQ / 8; t8++) {
        uint4 pk = *(const uint4*)(xwp + t8 * 8);
        unsigned wbits[4] = {pk.x, pk.y, pk.z, pk.w};
#pragma unroll
        for (int s = 0; s < 8; s++) {
            unsigned wb = wbits[s >> 1];
            float xf = (s & 1) ? __uint_as_float(wb & 0xffff0000u)
                               : __uint_as_float(wb << 16);
            float a0 = xf, a1 = 0.f, a2 = 0.f, a3 = 0.f;
#pragma unroll
            for (int k = 0; k < HID; k += 4) {
                a0 = fmaf(w[k + 0], h[k + 0], a0);
                a1 = fmaf(w[k + 1], h[k + 1], a1);
                a2 = fmaf(w[k + 2], h[k + 2], a2);
                a3 = fmaf(w[k + 3], h[k + 3], a3);
            }
            float hn = tanh_fast((a0 + a1) + (a2 + a3));
            hrow[j] = hn; // ds_write_b32, 2-way (free) bank pattern
            // broadcast read-back: all 32 lanes of the half read same addrs
#pragma unroll
            for (int k4 = 0; k4 < HID / 4; k4++) {
                float4 hv = *(const float4*)&hrow[k4 * 4];
                h[k4 * 4 + 0] = hv.x;
                h[k4 * 4 + 1] = hv.y;
                h[k4 * 4 + 2] = hv.z;
                h[k4 * 4 + 3] = hv.w;
            }
        }
    }

    // FC head: h is replicated, lanes 0..NCLS-1 each produce one class
    if (j < NCLS) {
        const float* fw = fc_W + j * HID;
        float a0 = fc_b[j], a1 = 0.f, a2 = 0.f, a3 = 0.f;
#pragma unroll
        for (int k = 0; k < HID; k += 4) {
            a0 = fmaf(fw[k + 0], h[k + 0], a0);
            a1 = fmaf(fw[k + 1], h[k + 1], a1);
            a2 = fmaf(fw[k + 2], h[k + 2], a2);
            a3 = fmaf(fw[k + 3], h[k + 3], a3);
        }
        out[b * NCLS + j] = (a0 + a1) + (a2 + a3);
    }
}

extern "C" void kernel_launch(void* const* d_in, const int* in_sizes, int n_in,
                              void* d_out, int out_size, void* d_ws, size_t ws_size,
                              hipStream_t stream) {
    const float* x    = (const float*)d_in[0];
    const float* W_ih = (const float*)d_in[1];
    const float* W_hh = (const float*)d_in[2];
    const float* b_ih = (const float*)d_in[3];
    const float* b_hh = (const float*)d_in[4];
    const float* fc_W = (const float*)d_in[5];
    const float* fc_b = (const float*)d_in[6];
    float* out = (float*)d_out;

    unsigned short* xw_ws = (unsigned short*)d_ws; // needs B*H*S*2 = 64 MiB

    xw_kernel<<<BATCH / 2, 256, 0, stream>>>(x, W_ih, b_ih, b_hh, xw_ws);
    rnn_kernel<<<BATCH / 8, 256, 0, stream>>>(xw_ws, W_hh, fc_W, fc_b, out);
}

// Round 2
// 587.221 us; speedup vs baseline: 1.1250x; 1.1250x over previous
//
#include <hip/hip_runtime.h>
#include <hip/hip_bf16.h>

#define SEQ 512
#define FEAT 64
#define HID 32
#define NCLS 10
#define BATCH 2048
#define RP 65          // padded LDS row stride (floats): banks (l*65)%32 = l%32 -> conflict-free
#define CROWS 256      // t-rows staged per chunk (2 chunks per batch)

// ---------------------------------------------------------------------------
// Phase 1: XW[b][h][t] (bf16) = x[b][t][:] . W_ih[h][:] + (b_ih[h] + b_hh[h])
// Coalesced global float4 loads -> regs -> padded LDS -> compute.
// thread = (h-quarter = wave id [uniform], lane = row-group); each thread
// computes 8 h x 4 rows (rows l, l+64, l+128, l+192 of the chunk).
// W reads are single-address wave broadcasts; x reads 2 lanes/bank (free).
// ---------------------------------------------------------------------------
__global__ __launch_bounds__(256, 2) void xw_kernel(
    const float* __restrict__ x,     // [B, S, F]
    const float* __restrict__ W_ih,  // [H, F]
    const float* __restrict__ b_ih,  // [H]
    const float* __restrict__ b_hh,  // [H]
    unsigned short* __restrict__ xw) // [B, H, S] bf16 bits
{
    __shared__ float xs[CROWS * RP];  // 66560 B
    __shared__ float wl[HID * FEAT];  // 8192 B
    __shared__ float bias[HID];

    const int tid = threadIdx.x;
    const int b   = blockIdx.x;
    const int l   = tid & 63;
    const int hq  = __builtin_amdgcn_readfirstlane(tid >> 6); // wave-uniform h-quarter

    // stage W + fused bias
    for (int i = tid; i < HID * FEAT; i += 256) wl[i] = W_ih[i];
    if (tid < HID) bias[tid] = b_ih[tid] + b_hh[tid];

    const float4* xg = (const float4*)(x + (size_t)b * SEQ * FEAT);
    // 4096 float4 per chunk; 16 per thread, lane-contiguous (coalesced)

    float4 ld[16];
#pragma unroll
    for (int k = 0; k < 16; k++) ld[k] = xg[tid + 256 * k];

#pragma unroll 1
    for (int c = 0; c < 2; c++) {
        if (c) __syncthreads();  // all readers of previous chunk done
        // regs -> padded LDS
#pragma unroll
        for (int k = 0; k < 16; k++) {
            int idx = tid + 256 * k;     // float4 index within chunk
            int row = idx >> 4, col = idx & 15;
            *(float4*)&xs[row * RP + col * 4] = ld[k];
        }
        if (c == 0) {
#pragma unroll
            for (int k = 0; k < 16; k++) ld[k] = xg[4096 + tid + 256 * k];
        }
        __syncthreads();  // chunk visible (also covers wl/bias on c==0)

        float acc[8][4];
#pragma unroll
        for (int i = 0; i < 8; i++)
#pragma unroll
            for (int r = 0; r < 4; r++) acc[i][r] = 0.f;

        const float* wbase = &wl[(hq * 8) * FEAT];

#pragma unroll 4
        for (int f4 = 0; f4 < 16; f4++) {
            float4 xv[4];
#pragma unroll
            for (int r = 0; r < 4; r++)
                xv[r] = *(const float4*)&xs[(l + 64 * r) * RP + f4 * 4];
#pragma unroll
            for (int i = 0; i < 8; i++) {
                float4 wv = *(const float4*)&wbase[i * FEAT + f4 * 4];
#pragma unroll
                for (int r = 0; r < 4; r++) {
                    acc[i][r] = fmaf(xv[r].x, wv.x, acc[i][r]);
                    acc[i][r] = fmaf(xv[r].y, wv.y, acc[i][r]);
                    acc[i][r] = fmaf(xv[r].z, wv.z, acc[i][r]);
                    acc[i][r] = fmaf(xv[r].w, wv.w, acc[i][r]);
                }
            }
        }

        const int t0 = c * CROWS;
#pragma unroll
        for (int i = 0; i < 8; i++) {
            int h = hq * 8 + i;
            float bv = bias[h];
            unsigned short* dst = xw + ((size_t)b * HID + h) * SEQ + t0 + l;
#pragma unroll
            for (int r = 0; r < 4; r++) {
                __hip_bfloat16 q = __float2bfloat16(acc[i][r] + bv);
                dst[64 * r] = *(unsigned short*)&q;  // 64 lanes x 2B contiguous
            }
        }
    }
}

// ---------------------------------------------------------------------------
// Phase 2: recurrence + FC head.
// 1 wave per block, 4 batches per wave: lanes 0-31 = batches (4B+0, 4B+1),
// lanes 32-63 = (4B+2, 4B+3); 2 independent chains per lane so the LDS
// h-broadcast latency of one chain hides under the other's FMAs.
// Next xw uint4 (8 steps) prefetched per chain at loop top.
// ---------------------------------------------------------------------------
__device__ __forceinline__ float tanh_fast(float v) {
    float e = __expf(-2.f * v);          // v_exp path
    return (1.f - e) * __frcp_rn(1.f + e);
}

__global__ __launch_bounds__(64) void rnn_kernel(
    const unsigned short* __restrict__ xw, // [B, H, S] bf16 bits
    const float* __restrict__ W_hh,        // [H, H]
    const float* __restrict__ fc_W,        // [NCLS, H]
    const float* __restrict__ fc_b,        // [NCLS]
    float* __restrict__ out)               // [B, NCLS]
{
    __shared__ float hl[4][HID];  // 2 groups x 2 chains

    const int l  = threadIdx.x;
    const int j  = l & 31;
    const int g  = l >> 5;
    const int b0 = blockIdx.x * 4 + g * 2;
    const int b1 = b0 + 1;

    float w[HID];
#pragma unroll
    for (int k = 0; k < HID; k++) w[k] = W_hh[j * HID + k];

    float h0[HID], h1[HID];
#pragma unroll
    for (int k = 0; k < HID; k++) { h0[k] = 0.f; h1[k] = 0.f; }

    const uint4* p0 = (const uint4*)(xw + ((size_t)b0 * HID + j) * SEQ);
    const uint4* p1 = (const uint4*)(xw + ((size_t)b1 * HID + j) * SEQ);
    uint4 cur0 = p0[0], cur1 = p1[0];

    float* r0 = hl[g * 2 + 0];
    float* r1 = hl[g * 2 + 1];

#pragma unroll 1
    for (int t8 = 0; t8 < SEQ / 8; t8++) {
        const int tn = (t8 + 1 < SEQ / 8) ? t8 + 1 : t8;
        uint4 nxt0 = p0[tn], nxt1 = p1[tn];  // in flight across the 8 steps
        unsigned c0[4] = {cur0.x, cur0.y, cur0.z, cur0.w};
        unsigned c1[4] = {cur1.x, cur1.y, cur1.z, cur1.w};
#pragma unroll
        for (int s = 0; s < 8; s++) {
            unsigned w0 = c0[s >> 1], w1 = c1[s >> 1];
            float xf0 = (s & 1) ? __uint_as_float(w0 & 0xffff0000u)
                                : __uint_as_float(w0 << 16);
            float xf1 = (s & 1) ? __uint_as_float(w1 & 0xffff0000u)
                                : __uint_as_float(w1 << 16);
            float a00 = xf0, a01 = 0.f, a02 = 0.f, a03 = 0.f;
            float a10 = xf1, a11 = 0.f, a12 = 0.f, a13 = 0.f;
#pragma unroll
            for (int k = 0; k < HID; k += 4) {
                a00 = fmaf(w[k + 0], h0[k + 0], a00);
                a10 = fmaf(w[k + 0], h1[k + 0], a10);
                a01 = fmaf(w[k + 1], h0[k + 1], a01);
                a11 = fmaf(w[k + 1], h1[k + 1], a11);
                a02 = fmaf(w[k + 2], h0[k + 2], a02);
                a12 = fmaf(w[k + 2], h1[k + 2], a12);
                a03 = fmaf(w[k + 3], h0[k + 3], a03);
                a13 = fmaf(w[k + 3], h1[k + 3], a13);
            }
            float hn0 = tanh_fast((a00 + a01) + (a02 + a03));
            float hn1 = tanh_fast((a10 + a11) + (a12 + a13));
            r0[j] = hn0;   // wave-local; DS pipe is in-order per wave
            r1[j] = hn1;
#pragma unroll
            for (int k4 = 0; k4 < HID / 4; k4++) {
                float4 v0 = *(const float4*)&r0[k4 * 4];
                float4 v1 = *(const float4*)&r1[k4 * 4];
                h0[k4 * 4 + 0] = v0.x; h0[k4 * 4 + 1] = v0.y;
                h0[k4 * 4 + 2] = v0.z; h0[k4 * 4 + 3] = v0.w;
                h1[k4 * 4 + 0] = v1.x; h1[k4 * 4 + 1] = v1.y;
                h1[k4 * 4 + 2] = v1.z; h1[k4 * 4 + 3] = v1.w;
            }
        }
        cur0 = nxt0; cur1 = nxt1;
    }

    if (j < NCLS) {
        const float* fw = fc_W + j * HID;
        float s0 = fc_b[j], s1 = fc_b[j];
        float t0a = 0.f, t1a = 0.f;
#pragma unroll
        for (int k = 0; k < HID; k += 2) {
            s0  = fmaf(fw[k], h0[k], s0);
            s1  = fmaf(fw[k], h1[k], s1);
            t0a = fmaf(fw[k + 1], h0[k + 1], t0a);
            t1a = fmaf(fw[k + 1], h1[k + 1], t1a);
        }
        out[b0 * NCLS + j] = s0 + t0a;
        out[b1 * NCLS + j] = s1 + t1a;
    }
}

extern "C" void kernel_launch(void* const* d_in, const int* in_sizes, int n_in,
                              void* d_out, int out_size, void* d_ws, size_t ws_size,
                              hipStream_t stream) {
    const float* x    = (const float*)d_in[0];
    const float* W_ih = (const float*)d_in[1];
    const float* W_hh = (const float*)d_in[2];
    const float* b_ih = (const float*)d_in[3];
    const float* b_hh = (const float*)d_in[4];
    const float* fc_W = (const float*)d_in[5];
    const float* fc_b = (const float*)d_in[6];
    float* out = (float*)d_out;

    unsigned short* xw_ws = (unsigned short*)d_ws; // B*H*S*2 = 64 MiB

    xw_kernel<<<BATCH, 256, 0, stream>>>(x, W_ih, b_ih, b_hh, xw_ws);
    rnn_kernel<<<BATCH / 4, 64, 0, stream>>>(xw_ws, W_hh, fc_W, fc_b, out);
}